// Round 13
// baseline (284.331 us; speedup 1.0000x reference)
//
#include <hip/hip_runtime.h>
#include <hip/hip_cooperative_groups.h>
#include <hip/hip_fp16.h>
#include <math.h>

namespace cg = cooperative_groups;

#define VOXSZ 0.04f
#define NV 9
#define NC 24
#define NH 120
#define NW 160
#define NBINS 262144        // 18-bit full-resolution morton key
#define TBLOCKS (NV * NH)   // 1080 transpose units
#define PLANE_BYTES ((size_t)NV * NH * NW * 16)  // 16 B/pixel per plane

// ---------------------------------------------------------------------------
// ws layout:
//   [0,64):  2 f32 scalars (zmean, zstd)
//   [64,+):  per-block partials (4 doubles each)
//   then:    featsT fp16 as 3 planes of 16 B/pixel (plane p = ch 8p..8p+7),
//            hist[NBINS], ofs[NBINS], bsum[256], sorted[N] int2
// ---------------------------------------------------------------------------

__device__ __forceinline__ int morton6(int a) {   // 6 bits -> every 3rd bit
  a = (a | (a << 8)) & 0x300F;
  a = (a | (a << 4)) & 0x30C3;
  a = (a | (a << 2)) & 0x9249;
  return a;
}

__device__ __forceinline__ int voxel_key(int4 cd) {
  int x = min(max(cd.y, 0), 63), y = min(max(cd.z, 0), 63), z = min(max(cd.w, 0), 63);
  return morton6(x) | (morton6(y) << 1) | (morton6(z) << 2);
}

// ===== fused cooperative kernel: zero -> prep -> scanA -> scanB -> scatter ==
__global__ __launch_bounds__(256, 4)
void fused_prep_sort_k(const float* __restrict__ feats, __half* __restrict__ featsT,
                       const int4* __restrict__ coords, const float* __restrict__ origin,
                       const float* __restrict__ proj, int* __restrict__ hist,
                       int* __restrict__ ofs, int* __restrict__ bsum,
                       double* __restrict__ partials, float* __restrict__ scal,
                       int2* __restrict__ sorted, float* __restrict__ out, int N) {
  cg::grid_group grid = cg::this_grid();
  int tid = threadIdx.x;
  int bid = blockIdx.x;
  int G = gridDim.x;

  __shared__ __half s[NC][NW + 2];
  __shared__ float s_proj[NV * 12];
  __shared__ float s_org[3];
  __shared__ double s_red[3][4];
  __shared__ int red[256];
  __shared__ int sb[256];
  __shared__ int st[256];

  if (tid < NV * 12) s_proj[tid] = proj[(tid / 12) * 16 + (tid % 12)];
  if (tid < 3) s_org[tid] = origin[tid];

  const int SUNITS = (N + 255) / 256;

  // ---- P0: zero hist (1 MB) ----
  for (int i = bid * 256 + tid; i < NBINS / 4; i += G * 256)
    ((int4*)hist)[i] = make_int4(0, 0, 0, 0);
  grid.sync();

  // ---- P1: transpose units + hist/stats/count units ----
  for (int u = bid; u < TBLOCKS + SUNITS; u += G) {
    if (u < TBLOCKS) {
      int v = u / NH, h = u % NH;
      const float* ibase = feats + (size_t)v * NC * NH * NW + (size_t)h * NW;
      for (int e = tid; e < NC * (NW / 4); e += 256) {
        int c = e / (NW / 4), w4 = e - c * (NW / 4);
        float4 f = *(const float4*)(ibase + (size_t)c * NH * NW + w4 * 4);
        int w = w4 * 4;
        s[c][w]     = __float2half(f.x);
        s[c][w + 1] = __float2half(f.y);
        s[c][w + 2] = __float2half(f.z);
        s[c][w + 3] = __float2half(f.w);
      }
      __syncthreads();
      for (int j = tid; j < NW * 12; j += 256) {
        int p = j / (NW * 4);
        int rem = j - p * (NW * 4);
        int w = rem >> 2, k = rem & 3;
        __half2 hv = __halves2half2(s[8 * p + 2 * k][w], s[8 * p + 2 * k + 1][w]);
        unsigned int* obase =
            (unsigned int*)((char*)featsT + (size_t)p * PLANE_BYTES) + (size_t)u * NW * 4;
        obase[(w << 2) | k] = *(unsigned int*)&hv;
      }
      __syncthreads();
    } else {
      int sid = u - TBLOCKS;
      int n = sid * 256 + tid;
      double rz = 0.0, rz2 = 0.0, rv = 0.0;
      if (n < N) {
        int4 cd = coords[n];
        atomicAdd(&hist[voxel_key(cd)], 1);
        float wx = (float)cd.y * VOXSZ + s_org[0];
        float wy = (float)cd.z * VOXSZ + s_org[1];
        float wz = (float)cd.w * VOXSZ + s_org[2];
        float zs = 0.f; int cnt = 0;
#pragma unroll
        for (int v = 0; v < NV; ++v) {
          const float* P = &s_proj[v * 12];
          float ix = P[0] * wx + P[1] * wy + P[2]  * wz + P[3];
          float iy = P[4] * wx + P[5] * wy + P[6]  * wz + P[7];
          float iz = P[8] * wx + P[9] * wy + P[10] * wz + P[11];
          float px = ix / iz, py = iy / iz;
          bool inb = (px >= 0.f) && (px <= (float)(NW - 1)) &&
                     (py >= 0.f) && (py <= (float)(NH - 1)) && (iz > 0.f);
          if (inb) { cnt++; zs += iz; }
        }
        out[(size_t)N * (NC + 1) + n] = (float)cnt;   // coalesced count
        if (cnt > 0) {
          float zsv = zs / (float)cnt;
          rz = (double)zsv; rz2 = (double)zsv * (double)zsv; rv = 1.0;
        }
      }
#pragma unroll
      for (int off = 32; off > 0; off >>= 1) {
        rz  += __shfl_down(rz,  off, 64);
        rz2 += __shfl_down(rz2, off, 64);
        rv  += __shfl_down(rv,  off, 64);
      }
      if ((tid & 63) == 0) {
        int w = tid >> 6;
        s_red[0][w] = rz; s_red[1][w] = rz2; s_red[2][w] = rv;
      }
      __syncthreads();
      if (tid == 0) {
        double a = 0, b = 0, c = 0;
#pragma unroll
        for (int w = 0; w < 4; ++w) { a += s_red[0][w]; b += s_red[1][w]; c += s_red[2][w]; }
        double* p = partials + (size_t)sid * 4;
        p[0] = a; p[1] = b; p[2] = c;
      }
      __syncthreads();
    }
  }
  grid.sync();

  // ---- P2: scanA (256 chunk sums) + stats finalize (unit 256) ----
  for (int u = bid; u < 257; u += G) {
    if (u < 256) {
      int4 h = ((const int4*)hist)[u * 256 + tid];
      red[tid] = h.x + h.y + h.z + h.w;
      __syncthreads();
      for (int off = 128; off > 0; off >>= 1) {
        if (tid < off) red[tid] += red[tid + off];
        __syncthreads();
      }
      if (tid == 0) bsum[u] = red[0];
      __syncthreads();
    } else {
      double rz = 0.0, rz2 = 0.0, rv = 0.0;
      for (int i = tid; i < SUNITS; i += 256) {
        const double* p = partials + (size_t)i * 4;
        rz += p[0]; rz2 += p[1]; rv += p[2];
      }
#pragma unroll
      for (int off = 32; off > 0; off >>= 1) {
        rz  += __shfl_down(rz,  off, 64);
        rz2 += __shfl_down(rz2, off, 64);
        rv  += __shfl_down(rv,  off, 64);
      }
      if ((tid & 63) == 0) {
        int w = tid >> 6;
        s_red[0][w] = rz; s_red[1][w] = rz2; s_red[2][w] = rv;
      }
      __syncthreads();
      if (tid == 0) {
        double sz = 0, sz2 = 0, nv = 0;
#pragma unroll
        for (int w = 0; w < 4; ++w) { sz += s_red[0][w]; sz2 += s_red[1][w]; nv += s_red[2][w]; }
        double nvm = (nv > 1.0) ? nv : 1.0;
        double zmean = sz / nvm;
        double var = sz2 - 2.0 * zmean * sz + zmean * zmean * nv;
        if (var < 0.0) var = 0.0;
        scal[0] = (float)zmean;
        scal[1] = (float)(sqrt(var) + 1e-5);
      }
      __syncthreads();
    }
  }
  grid.sync();

  // ---- P3: scanB (256 units) ----
  if (bid < 256) {
    sb[tid] = bsum[tid];
    __syncthreads();
    for (int off = 1; off < 256; off <<= 1) {
      int v = (tid >= off) ? sb[tid - off] : 0;
      __syncthreads();
      sb[tid] += v;
      __syncthreads();
    }
    int base_blk = (bid == 0) ? 0 : sb[bid - 1];
    int idx = bid * 256 + tid;
    int4 h = ((const int4*)hist)[idx];
    int tsum = h.x + h.y + h.z + h.w;
    st[tid] = tsum;
    __syncthreads();
    for (int off = 1; off < 256; off <<= 1) {
      int v = (tid >= off) ? st[tid - off] : 0;
      __syncthreads();
      st[tid] += v;
      __syncthreads();
    }
    int base = base_blk + st[tid] - tsum;
    int4 o;
    o.x = base;
    o.y = base + h.x;
    o.z = o.y + h.y;
    o.w = o.z + h.z;
    ((int4*)ofs)[idx] = o;
  }
  grid.sync();

  // ---- P4: scatter ----
  for (int u = bid; u < SUNITS; u += G) {
    int n = u * 256 + tid;
    if (n < N) {
      int4 cd = coords[n];
      int pos = atomicAdd(&ofs[voxel_key(cd)], 1);
      sorted[pos] = make_int2(cd.y | (cd.z << 7) | (cd.w << 14), n);
    }
  }
}

// ===== fallback (non-cooperative) versions ==================================
__global__ __launch_bounds__(256)
void zero_hist_k(int4* __restrict__ hist4) {
  hist4[blockIdx.x * 256 + threadIdx.x] = make_int4(0, 0, 0, 0);
}

__global__ __launch_bounds__(256)
void prep_k(const float* __restrict__ feats, __half* __restrict__ outT,
            const int4* __restrict__ coords, const float* __restrict__ origin,
            const float* __restrict__ proj, int* __restrict__ hist,
            double* __restrict__ partials, float* __restrict__ out, int N) {
  __shared__ __half s[NC][NW + 2];
  __shared__ float s_proj[NV * 12];
  __shared__ float s_org[3];
  __shared__ double s_red[3][4];
  int tid = threadIdx.x;

  if (blockIdx.x < TBLOCKS) {
    int vh = blockIdx.x;
    int v = vh / NH, h = vh % NH;
    const float* ibase = feats + (size_t)v * NC * NH * NW + (size_t)h * NW;
    for (int e = tid; e < NC * (NW / 4); e += 256) {
      int c = e / (NW / 4), w4 = e - c * (NW / 4);
      float4 f = *(const float4*)(ibase + (size_t)c * NH * NW + w4 * 4);
      int w = w4 * 4;
      s[c][w]     = __float2half(f.x);
      s[c][w + 1] = __float2half(f.y);
      s[c][w + 2] = __float2half(f.z);
      s[c][w + 3] = __float2half(f.w);
    }
    __syncthreads();
    for (int j = tid; j < NW * 12; j += 256) {
      int p = j / (NW * 4);
      int rem = j - p * (NW * 4);
      int w = rem >> 2, k = rem & 3;
      __half2 hv = __halves2half2(s[8 * p + 2 * k][w], s[8 * p + 2 * k + 1][w]);
      unsigned int* obase =
          (unsigned int*)((char*)outT + (size_t)p * PLANE_BYTES) + (size_t)vh * NW * 4;
      obase[(w << 2) | k] = *(unsigned int*)&hv;
    }
    return;
  }

  if (tid < NV * 12) s_proj[tid] = proj[(tid / 12) * 16 + (tid % 12)];
  if (tid < 3) s_org[tid] = origin[tid];
  __syncthreads();

  int sid = blockIdx.x - TBLOCKS;
  int n = sid * 256 + tid;
  double rz = 0.0, rz2 = 0.0, rv = 0.0;
  if (n < N) {
    int4 cd = coords[n];
    atomicAdd(&hist[voxel_key(cd)], 1);
    float wx = (float)cd.y * VOXSZ + s_org[0];
    float wy = (float)cd.z * VOXSZ + s_org[1];
    float wz = (float)cd.w * VOXSZ + s_org[2];
    float zs = 0.f; int cnt = 0;
#pragma unroll
    for (int v = 0; v < NV; ++v) {
      const float* P = &s_proj[v * 12];
      float ix = P[0] * wx + P[1] * wy + P[2]  * wz + P[3];
      float iy = P[4] * wx + P[5] * wy + P[6]  * wz + P[7];
      float iz = P[8] * wx + P[9] * wy + P[10] * wz + P[11];
      float px = ix / iz, py = iy / iz;
      bool inb = (px >= 0.f) && (px <= (float)(NW - 1)) &&
                 (py >= 0.f) && (py <= (float)(NH - 1)) && (iz > 0.f);
      if (inb) { cnt++; zs += iz; }
    }
    out[(size_t)N * (NC + 1) + n] = (float)cnt;
    if (cnt > 0) {
      float zsv = zs / (float)cnt;
      rz = (double)zsv; rz2 = (double)zsv * (double)zsv; rv = 1.0;
    }
  }
#pragma unroll
  for (int off = 32; off > 0; off >>= 1) {
    rz  += __shfl_down(rz,  off, 64);
    rz2 += __shfl_down(rz2, off, 64);
    rv  += __shfl_down(rv,  off, 64);
  }
  if ((tid & 63) == 0) {
    int w = tid >> 6;
    s_red[0][w] = rz; s_red[1][w] = rz2; s_red[2][w] = rv;
  }
  __syncthreads();
  if (tid == 0) {
    double a = 0, b = 0, c = 0;
#pragma unroll
    for (int w = 0; w < 4; ++w) { a += s_red[0][w]; b += s_red[1][w]; c += s_red[2][w]; }
    double* p = partials + (size_t)sid * 4;
    p[0] = a; p[1] = b; p[2] = c;
  }
}

__global__ __launch_bounds__(256)
void scanA_k(const int* __restrict__ hist, int* __restrict__ bsum,
             const double* __restrict__ partials, int nblocks,
             float* __restrict__ scal) {
  int tid = threadIdx.x;
  if (blockIdx.x == 256) {
    double rz = 0.0, rz2 = 0.0, rv = 0.0;
    for (int i = tid; i < nblocks; i += 256) {
      const double* p = partials + (size_t)i * 4;
      rz += p[0]; rz2 += p[1]; rv += p[2];
    }
#pragma unroll
    for (int off = 32; off > 0; off >>= 1) {
      rz  += __shfl_down(rz,  off, 64);
      rz2 += __shfl_down(rz2, off, 64);
      rv  += __shfl_down(rv,  off, 64);
    }
    __shared__ double s[3][4];
    if ((tid & 63) == 0) {
      int w = tid >> 6;
      s[0][w] = rz; s[1][w] = rz2; s[2][w] = rv;
    }
    __syncthreads();
    if (tid == 0) {
      double sz = 0, sz2 = 0, nv = 0;
#pragma unroll
      for (int w = 0; w < 4; ++w) { sz += s[0][w]; sz2 += s[1][w]; nv += s[2][w]; }
      double nvm = (nv > 1.0) ? nv : 1.0;
      double zmean = sz / nvm;
      double var = sz2 - 2.0 * zmean * sz + zmean * zmean * nv;
      if (var < 0.0) var = 0.0;
      scal[0] = (float)zmean;
      scal[1] = (float)(sqrt(var) + 1e-5);
    }
    return;
  }
  __shared__ int red[256];
  int4 h = ((const int4*)hist)[blockIdx.x * 256 + tid];
  red[tid] = h.x + h.y + h.z + h.w;
  __syncthreads();
  for (int off = 128; off > 0; off >>= 1) {
    if (tid < off) red[tid] += red[tid + off];
    __syncthreads();
  }
  if (tid == 0) bsum[blockIdx.x] = red[0];
}

__global__ __launch_bounds__(256)
void scanB_k(const int* __restrict__ hist, const int* __restrict__ bsum,
             int* __restrict__ ofs) {
  __shared__ int sb[256];
  __shared__ int st[256];
  int tid = threadIdx.x;
  sb[tid] = bsum[tid];
  __syncthreads();
  for (int off = 1; off < 256; off <<= 1) {
    int v = (tid >= off) ? sb[tid - off] : 0;
    __syncthreads();
    sb[tid] += v;
    __syncthreads();
  }
  int base_blk = (blockIdx.x == 0) ? 0 : sb[blockIdx.x - 1];
  int idx = blockIdx.x * 256 + tid;
  int4 h = ((const int4*)hist)[idx];
  int tsum = h.x + h.y + h.z + h.w;
  st[tid] = tsum;
  __syncthreads();
  for (int off = 1; off < 256; off <<= 1) {
    int v = (tid >= off) ? st[tid - off] : 0;
    __syncthreads();
    st[tid] += v;
    __syncthreads();
  }
  int base = base_blk + st[tid] - tsum;
  int4 o;
  o.x = base;
  o.y = base + h.x;
  o.z = o.y + h.y;
  o.w = o.z + h.z;
  ((int4*)ofs)[idx] = o;
}

__global__ __launch_bounds__(256)
void scatter_k(const int4* __restrict__ coords, int* __restrict__ ofs,
               int2* __restrict__ sorted, int N) {
  int n = blockIdx.x * blockDim.x + threadIdx.x;
  if (n >= N) return;
  int4 cd = coords[n];
  int pos = atomicAdd(&ofs[voxel_key(cd)], 1);
  sorted[pos] = make_int2(cd.y | (cd.z << 7) | (cd.w << 14), n);
}

// ===== main gather (unchanged from round 12) ================================
__global__ __launch_bounds__(192, 4)
void bp_gather_k(const int2* __restrict__ sorted, const float* __restrict__ origin,
                 const float* __restrict__ proj, const __half* __restrict__ featsT,
                 const float* __restrict__ scal, float* __restrict__ out, int N) {
  __shared__ float s_proj[NV * 12];
  __shared__ float s_org[3];
  __shared__ float s_scal[2];
  __shared__ uint2 s_offd[NV][64];
  __shared__ uint4 s_w2[NV][64];
  __shared__ float s_zs[3][64];
  __shared__ int   s_cnt[3][64];
  int tid = threadIdx.x;
  if (tid < NV * 12) s_proj[tid] = proj[(tid / 12) * 16 + (tid % 12)];
  if (tid < 3) s_org[tid] = origin[tid];
  if (tid < 2) s_scal[tid] = scal[tid];
  __syncthreads();

  int nwg = gridDim.x, orig = blockIdx.x;
  int xcd = orig & 7, q = nwg >> 3, r = nwg & 7;
  int bid = (xcd < r ? xcd * (q + 1) : r * (q + 1) + (xcd - r) * q) + (orig >> 3);

  int lane = tid & 63, part = tid >> 6;
  int i = bid * 64 + lane;
  int n = -1, xi = 0, yi = 0, zi = 0;
  if (i < N) {
    int2 rec = sorted[i];
    n = rec.y;
    xi = rec.x & 127; yi = (rec.x >> 7) & 127; zi = (rec.x >> 14) & 127;
  }
  float wx = (float)xi * VOXSZ + s_org[0];
  float wy = (float)yi * VOXSZ + s_org[1];
  float wz = (float)zi * VOXSZ + s_org[2];
  float vm = (n >= 0) ? 1.f : 0.f;

  float zsp = 0.f; int cntp = 0;
#pragma unroll
  for (int qv = 0; qv < 3; ++qv) {
    int v = 3 * part + qv;
    const float* P = &s_proj[v * 12];
    float ix = P[0] * wx + P[1] * wy + P[2]  * wz + P[3];
    float iy = P[4] * wx + P[5] * wy + P[6]  * wz + P[7];
    float iz = P[8] * wx + P[9] * wy + P[10] * wz + P[11];
    float px = ix / iz, py = iy / iz;
    bool inb = (px >= 0.f) && (px <= (float)(NW - 1)) &&
               (py >= 0.f) && (py <= (float)(NH - 1)) && (iz > 0.f);
    float wm = inb ? vm : 0.f;
    cntp += (wm > 0.f) ? 1 : 0;
    zsp = fmaf(wm, iz, zsp);
    float pxc = fminf(fmaxf(px, 0.f), (float)(NW - 1));
    float pyc = fminf(fmaxf(py, 0.f), (float)(NH - 1));
    float x0f = floorf(pxc), y0f = floorf(pyc);
    float fx1 = pxc - x0f, fy1 = pyc - y0f;
    float fx0 = 1.f - fx1, fy0 = 1.f - fy1;
    int x0 = (int)x0f, y0 = (int)y0f;
    unsigned dx = (x0 + 1 < NW) ? 16u : 0u;
    unsigned dy = (y0 + 1 < NH) ? (unsigned)(NW * 16) : 0u;
    unsigned off = (unsigned)(((y0 + v * NH) * NW + x0) * 16);
    __half2 h00 = __float2half2_rn(fx0 * fy0 * wm);
    __half2 h10 = __float2half2_rn(fx1 * fy0 * wm);
    __half2 h01 = __float2half2_rn(fx0 * fy1 * wm);
    __half2 h11 = __float2half2_rn(fx1 * fy1 * wm);
    s_offd[v][lane] = make_uint2(off, dx | (dy << 16));
    uint4 wv;
    wv.x = *(unsigned int*)&h00;
    wv.y = *(unsigned int*)&h10;
    wv.z = *(unsigned int*)&h01;
    wv.w = *(unsigned int*)&h11;
    s_w2[v][lane] = wv;
  }
  s_zs[part][lane] = zsp;
  s_cnt[part][lane] = cntp;
  __syncthreads();

  int cnt = s_cnt[0][lane] + s_cnt[1][lane] + s_cnt[2][lane];
  __half2 acc2[4];
  const __half2 zero2 = __float2half2_rn(0.f);
#pragma unroll
  for (int c = 0; c < 4; ++c) acc2[c] = zero2;
  const char* fbase = (const char*)featsT + (size_t)part * PLANE_BYTES;

#pragma unroll
  for (int v = 0; v < NV; ++v) {
    uint4 wv = s_w2[v][lane];
    if ((wv.x | wv.y | wv.z | wv.w) == 0u) continue;
    uint2 od = s_offd[v][lane];
    unsigned dx = od.y & 0xFFFFu, dy = od.y >> 16;
    const char* p00 = fbase + od.x;
    float4 c00 = *(const float4*)p00;
    float4 c10 = *(const float4*)(p00 + dx);
    float4 c01 = *(const float4*)(p00 + dy);
    float4 c11 = *(const float4*)(p00 + dx + dy);
    __half2 w00 = *(__half2*)&wv.x;
    __half2 w10 = *(__half2*)&wv.y;
    __half2 w01 = *(__half2*)&wv.z;
    __half2 w11 = *(__half2*)&wv.w;
    const __half2* h00 = (const __half2*)&c00;
    const __half2* h10 = (const __half2*)&c10;
    const __half2* h01 = (const __half2*)&c01;
    const __half2* h11 = (const __half2*)&c11;
#pragma unroll
    for (int c = 0; c < 4; ++c) acc2[c] = __hfma2(w00, h00[c], acc2[c]);
#pragma unroll
    for (int c = 0; c < 4; ++c) acc2[c] = __hfma2(w10, h10[c], acc2[c]);
#pragma unroll
    for (int c = 0; c < 4; ++c) acc2[c] = __hfma2(w01, h01[c], acc2[c]);
#pragma unroll
    for (int c = 0; c < 4; ++c) acc2[c] = __hfma2(w11, h11[c], acc2[c]);
  }

  if (n < 0) return;
  float denom = (cnt > 0) ? (float)cnt : 1.f;
  float inv = 1.f / denom;
  size_t row = (size_t)n * (NC + 1) + part * 8;
#pragma unroll
  for (int c = 0; c < 4; ++c) {
    float2 t = __half22float2(acc2[c]);
    out[row + 2 * c]     = t.x * inv;
    out[row + 2 * c + 1] = t.y * inv;
  }
  if (part == 2) {
    float zs = s_zs[0][lane] + s_zs[1][lane] + s_zs[2][lane];
    float zsv = zs * inv;
    out[(size_t)n * (NC + 1) + NC] = (cnt > 0) ? (zsv - s_scal[0]) / s_scal[1] : 0.f;
  }
}

// ---- fallback path (ws too small): projection stats + direct f32 gather ----
__global__ __launch_bounds__(256)
void stats_k(const int4* __restrict__ coords, const float* __restrict__ origin,
             const float* __restrict__ proj, double* __restrict__ partials, int N) {
  __shared__ float s_proj[NV * 12];
  __shared__ float s_org[3];
  __shared__ double s_red[3][4];
  int tid = threadIdx.x;
  if (tid < NV * 12) s_proj[tid] = proj[(tid / 12) * 16 + (tid % 12)];
  if (tid < 3) s_org[tid] = origin[tid];
  __syncthreads();
  int n = blockIdx.x * blockDim.x + tid;
  double rz = 0.0, rz2 = 0.0, rv = 0.0;
  if (n < N) {
    int4 cd = coords[n];
    float wx = (float)cd.y * VOXSZ + s_org[0];
    float wy = (float)cd.z * VOXSZ + s_org[1];
    float wz = (float)cd.w * VOXSZ + s_org[2];
    float zs = 0.f; int cnt = 0;
#pragma unroll
    for (int v = 0; v < NV; ++v) {
      const float* P = &s_proj[v * 12];
      float ix = P[0] * wx + P[1] * wy + P[2]  * wz + P[3];
      float iy = P[4] * wx + P[5] * wy + P[6]  * wz + P[7];
      float iz = P[8] * wx + P[9] * wy + P[10] * wz + P[11];
      float px = ix / iz, py = iy / iz;
      bool inb = (px >= 0.f) && (px <= (float)(NW - 1)) &&
                 (py >= 0.f) && (py <= (float)(NH - 1)) && (iz > 0.f);
      if (inb) { cnt++; zs += iz; }
    }
    if (cnt > 0) {
      float zsv = zs / (float)cnt;
      rz = (double)zsv; rz2 = (double)zsv * (double)zsv; rv = 1.0;
    }
  }
#pragma unroll
  for (int off = 32; off > 0; off >>= 1) {
    rz  += __shfl_down(rz,  off, 64);
    rz2 += __shfl_down(rz2, off, 64);
    rv  += __shfl_down(rv,  off, 64);
  }
  if ((tid & 63) == 0) {
    int w = tid >> 6;
    s_red[0][w] = rz; s_red[1][w] = rz2; s_red[2][w] = rv;
  }
  __syncthreads();
  if (tid == 0) {
    double a = 0, b = 0, c = 0;
#pragma unroll
    for (int w = 0; w < 4; ++w) { a += s_red[0][w]; b += s_red[1][w]; c += s_red[2][w]; }
    double* p = partials + (size_t)blockIdx.x * 4;
    p[0] = a; p[1] = b; p[2] = c;
  }
}

__global__ __launch_bounds__(1024)
void reduce_finalize_k(const double* __restrict__ partials, int nblocks,
                       float* __restrict__ scal) {
  int tid = threadIdx.x;
  double rz = 0.0, rz2 = 0.0, rv = 0.0;
  for (int i = tid; i < nblocks; i += 1024) {
    const double* p = partials + (size_t)i * 4;
    rz += p[0]; rz2 += p[1]; rv += p[2];
  }
#pragma unroll
  for (int off = 32; off > 0; off >>= 1) {
    rz  += __shfl_down(rz,  off, 64);
    rz2 += __shfl_down(rz2, off, 64);
    rv  += __shfl_down(rv,  off, 64);
  }
  __shared__ double s[3][16];
  if ((tid & 63) == 0) {
    int w = tid >> 6;
    s[0][w] = rz; s[1][w] = rz2; s[2][w] = rv;
  }
  __syncthreads();
  if (tid == 0) {
    double sz = 0, sz2 = 0, nv = 0;
#pragma unroll
    for (int w = 0; w < 16; ++w) { sz += s[0][w]; sz2 += s[1][w]; nv += s[2][w]; }
    double nvm = (nv > 1.0) ? nv : 1.0;
    double zmean = sz / nvm;
    double var = sz2 - 2.0 * zmean * sz + zmean * zmean * nv;
    if (var < 0.0) var = 0.0;
    scal[0] = (float)zmean;
    scal[1] = (float)(sqrt(var) + 1e-5);
  }
}

__global__ __launch_bounds__(256)
void bp_fallback_k(const int4* __restrict__ coords, const float* __restrict__ origin,
                   const float* __restrict__ proj, const float* __restrict__ feats,
                   const float* __restrict__ scal, float* __restrict__ out, int N) {
  __shared__ float s_proj[NV * 12];
  __shared__ float s_org[3];
  __shared__ float s_scal[2];
  int tid = threadIdx.x;
  if (tid < NV * 12) s_proj[tid] = proj[(tid / 12) * 16 + (tid % 12)];
  if (tid < 3) s_org[tid] = origin[tid];
  if (tid < 2) s_scal[tid] = scal[tid];
  __syncthreads();
  int n = blockIdx.x * blockDim.x + tid;
  if (n >= N) return;
  int4 cd = coords[n];
  float wx = (float)cd.y * VOXSZ + s_org[0];
  float wy = (float)cd.z * VOXSZ + s_org[1];
  float wz = (float)cd.w * VOXSZ + s_org[2];
  float acc[NC];
#pragma unroll
  for (int c = 0; c < NC; ++c) acc[c] = 0.f;
  float zs = 0.f; int cnt = 0;
#pragma unroll
  for (int v = 0; v < NV; ++v) {
    const float* P = &s_proj[v * 12];
    float ix = P[0] * wx + P[1] * wy + P[2]  * wz + P[3];
    float iy = P[4] * wx + P[5] * wy + P[6]  * wz + P[7];
    float iz = P[8] * wx + P[9] * wy + P[10] * wz + P[11];
    float px = ix / iz, py = iy / iz;
    bool inb = (px >= 0.f) && (px <= (float)(NW - 1)) &&
               (py >= 0.f) && (py <= (float)(NH - 1)) && (iz > 0.f);
    if (!inb) continue;
    cnt++; zs += iz;
    float x0f = floorf(px), y0f = floorf(py);
    float fx1 = px - x0f, fy1 = py - y0f;
    float fx0 = 1.f - fx1, fy0 = 1.f - fy1;
    int x0 = (int)x0f, y0 = (int)y0f;
    int x1 = (x0 + 1 < NW) ? x0 + 1 : NW - 1;
    int y1 = (y0 + 1 < NH) ? y0 + 1 : NH - 1;
    float w00 = fx0 * fy0, w10 = fx1 * fy0, w01 = fx0 * fy1, w11 = fx1 * fy1;
    const float* base = feats + (size_t)v * NC * NH * NW;
#pragma unroll
    for (int c = 0; c < NC; ++c) {
      const float* pc = base + (size_t)c * NH * NW;
      acc[c] += pc[y0 * NW + x0] * w00 + pc[y0 * NW + x1] * w10 +
                pc[y1 * NW + x0] * w01 + pc[y1 * NW + x1] * w11;
    }
  }
  float denom = (cnt > 0) ? (float)cnt : 1.f;
  float inv = 1.f / denom;
  size_t row = (size_t)n * (NC + 1);
#pragma unroll
  for (int c = 0; c < NC; ++c) out[row + c] = acc[c] * inv;
  float zsv = zs * inv;
  out[row + NC] = (cnt > 0) ? (zsv - s_scal[0]) / s_scal[1] : 0.f;
  out[(size_t)N * (NC + 1) + n] = (float)cnt;
}

extern "C" void kernel_launch(void* const* d_in, const int* in_sizes, int n_in,
                              void* d_out, int out_size, void* d_ws, size_t ws_size,
                              hipStream_t stream) {
  const int4*  coords = (const int4*)d_in[0];
  const float* origin = (const float*)d_in[1];
  const float* feats  = (const float*)d_in[2];
  const float* proj   = (const float*)d_in[3];
  float* out = (float*)d_out;
  int N = in_sizes[0] / 4;

  int blocksAll = (N + 255) / 256;

  char* ws = (char*)d_ws;
  float*  scal     = (float*)ws;                 // 2 floats
  double* partials = (double*)(ws + 64);
  size_t off = 64 + (size_t)blocksAll * 4 * sizeof(double);
  off = (off + 63) & ~(size_t)63;
  __half* featsT = (__half*)(ws + off);
  off += 3 * PLANE_BYTES;
  int* hist = (int*)(ws + off); off += (size_t)NBINS * sizeof(int);
  int* ofs  = (int*)(ws + off); off += (size_t)NBINS * sizeof(int);
  int* bsum = (int*)(ws + off); off += 256 * sizeof(int);
  off = (off + 15) & ~(size_t)15;
  int2* sorted = (int2*)(ws + off); off += (size_t)N * sizeof(int2);
  bool full = (ws_size >= off);

  if (full) {
    void* kargs[] = {(void*)&feats, (void*)&featsT, (void*)&coords, (void*)&origin,
                     (void*)&proj, (void*)&hist, (void*)&ofs, (void*)&bsum,
                     (void*)&partials, (void*)&scal, (void*)&sorted, (void*)&out,
                     (void*)&N};
    hipError_t err = hipLaunchCooperativeKernel((const void*)fused_prep_sort_k,
                                                dim3(512), dim3(256), kargs, 0, stream);
    if (err != hipSuccess) {
      // non-cooperative fallback: identical phases as separate dispatches
      zero_hist_k<<<NBINS / 1024, 256, 0, stream>>>((int4*)hist);
      prep_k<<<TBLOCKS + blocksAll, 256, 0, stream>>>(feats, featsT, coords, origin,
                                                      proj, hist, partials, out, N);
      scanA_k<<<257, 256, 0, stream>>>(hist, bsum, partials, blocksAll, scal);
      scanB_k<<<256, 256, 0, stream>>>(hist, bsum, ofs);
      scatter_k<<<blocksAll, 256, 0, stream>>>(coords, ofs, sorted, N);
    }
    int gblocks = (N + 63) / 64;
    bp_gather_k<<<gblocks, 192, 0, stream>>>(sorted, origin, proj, featsT, scal, out, N);
  } else {
    stats_k<<<blocksAll, 256, 0, stream>>>(coords, origin, proj, partials, N);
    reduce_finalize_k<<<1, 1024, 0, stream>>>(partials, blocksAll, scal);
    bp_fallback_k<<<blocksAll, 256, 0, stream>>>(coords, origin, proj, feats, scal, out, N);
  }
}

// Round 14
// 86.012 us; speedup vs baseline: 3.3057x; 3.3057x over previous
//
#include <hip/hip_runtime.h>
#include <hip/hip_fp16.h>
#include <math.h>

#define VOXSZ 0.04f
#define NV 9
#define NC 24
#define NH 120
#define NW 160
#define NBINS 32768         // 15-bit morton key of (x>>1, y>>1, z>>1), each 0..31
#define TBLOCKS (NV * NH)   // 1080 transpose blocks in prep_k
#define PLANE_BYTES ((size_t)NV * NH * NW * 16)  // 16 B/pixel per plane

// ---------------------------------------------------------------------------
// ws layout:
//   [0,64):  2 f32 scalars (zmean, zstd)
//   [64,+):  per-block partials (4 doubles each)
//   then:    featsT fp16 as 3 planes of 16 B/pixel (plane p = ch 8p..8p+7),
//            hist[NBINS], ofs[NBINS], bsum[32], sorted[N] int2
// ---------------------------------------------------------------------------

__device__ __forceinline__ int morton5(int a) {   // 5 bits -> every 3rd bit
  a = (a | (a << 8)) & 0x100F;
  a = (a | (a << 4)) & 0x10C3;
  a = (a | (a << 2)) & 0x1249;
  return a;
}

__device__ __forceinline__ int voxel_key(int4 cd) {
  // 2x2x2-voxel cells; clamp merges edge cells (locality only, not injective)
  int x = min(max(cd.y >> 1, 0), 31);
  int y = min(max(cd.z >> 1, 0), 31);
  int z = min(max(cd.w >> 1, 0), 31);
  return morton5(x) | (morton5(y) << 1) | (morton5(z) << 2);
}

// full-BW hist clear: 32 blocks x 256 threads x int4 = 128 KB
__global__ __launch_bounds__(256)
void zero_hist_k(int4* __restrict__ hist4) {
  hist4[blockIdx.x * 256 + threadIdx.x] = make_int4(0, 0, 0, 0);
}

// Fused prep: blocks [0,TBLOCKS) transpose feats; rest do hist + stats +
// coalesced per-voxel count output (count only depends on projections).
__global__ __launch_bounds__(256)
void prep_k(const float* __restrict__ feats, __half* __restrict__ outT,
            const int4* __restrict__ coords, const float* __restrict__ origin,
            const float* __restrict__ proj, int* __restrict__ hist,
            double* __restrict__ partials, float* __restrict__ out, int N) {
  __shared__ __half s[NC][NW + 2];
  __shared__ float s_proj[NV * 12];
  __shared__ float s_org[3];
  __shared__ double s_red[3][4];
  int tid = threadIdx.x;

  if (blockIdx.x < TBLOCKS) {
    // --- transpose role: f32 (V,C,H,W) -> 3 fp16 planes (V,H,W,8ch) ---
    int vh = blockIdx.x;
    int v = vh / NH, h = vh % NH;
    const float* ibase = feats + (size_t)v * NC * NH * NW + (size_t)h * NW;
    for (int e = tid; e < NC * (NW / 4); e += 256) {
      int c = e / (NW / 4), w4 = e - c * (NW / 4);
      float4 f = *(const float4*)(ibase + (size_t)c * NH * NW + w4 * 4);
      int w = w4 * 4;
      s[c][w]     = __float2half(f.x);
      s[c][w + 1] = __float2half(f.y);
      s[c][w + 2] = __float2half(f.z);
      s[c][w + 3] = __float2half(f.w);
    }
    __syncthreads();
    for (int j = tid; j < NW * 12; j += 256) {
      int p = j / (NW * 4);
      int rem = j - p * (NW * 4);
      int w = rem >> 2, k = rem & 3;
      __half2 hv = __halves2half2(s[8 * p + 2 * k][w], s[8 * p + 2 * k + 1][w]);
      unsigned int* obase =
          (unsigned int*)((char*)outT + (size_t)p * PLANE_BYTES) + (size_t)vh * NW * 4;
      obase[(w << 2) | k] = *(unsigned int*)&hv;
    }
    return;
  }

  // --- hist + stats + count role ---
  if (tid < NV * 12) s_proj[tid] = proj[(tid / 12) * 16 + (tid % 12)];
  if (tid < 3) s_org[tid] = origin[tid];
  __syncthreads();

  int sid = blockIdx.x - TBLOCKS;
  int n = sid * 256 + tid;
  double rz = 0.0, rz2 = 0.0, rv = 0.0;
  if (n < N) {
    int4 cd = coords[n];
    atomicAdd(&hist[voxel_key(cd)], 1);
    float wx = (float)cd.y * VOXSZ + s_org[0];
    float wy = (float)cd.z * VOXSZ + s_org[1];
    float wz = (float)cd.w * VOXSZ + s_org[2];
    float zs = 0.f; int cnt = 0;
#pragma unroll
    for (int v = 0; v < NV; ++v) {
      const float* P = &s_proj[v * 12];
      float ix = P[0] * wx + P[1] * wy + P[2]  * wz + P[3];
      float iy = P[4] * wx + P[5] * wy + P[6]  * wz + P[7];
      float iz = P[8] * wx + P[9] * wy + P[10] * wz + P[11];
      float px = ix / iz, py = iy / iz;
      bool inb = (px >= 0.f) && (px <= (float)(NW - 1)) &&
                 (py >= 0.f) && (py <= (float)(NH - 1)) && (iz > 0.f);
      if (inb) { cnt++; zs += iz; }
    }
    out[(size_t)N * (NC + 1) + n] = (float)cnt;   // coalesced count output
    if (cnt > 0) {
      float zsv = zs / (float)cnt;
      rz = (double)zsv; rz2 = (double)zsv * (double)zsv; rv = 1.0;
    }
  }
#pragma unroll
  for (int off = 32; off > 0; off >>= 1) {
    rz  += __shfl_down(rz,  off, 64);
    rz2 += __shfl_down(rz2, off, 64);
    rv  += __shfl_down(rv,  off, 64);
  }
  if ((tid & 63) == 0) {
    int w = tid >> 6;
    s_red[0][w] = rz; s_red[1][w] = rz2; s_red[2][w] = rv;
  }
  __syncthreads();
  if (tid == 0) {
    double a = 0, b = 0, c = 0;
#pragma unroll
    for (int w = 0; w < 4; ++w) { a += s_red[0][w]; b += s_red[1][w]; c += s_red[2][w]; }
    double* p = partials + (size_t)sid * 4;
    p[0] = a; p[1] = b; p[2] = c;
  }
}

// scanA: blocks 0..31 reduce 1024 bins each -> bsum[b]; block 32 finalizes stats
__global__ __launch_bounds__(256)
void scanA_k(const int* __restrict__ hist, int* __restrict__ bsum,
             const double* __restrict__ partials, int nblocks,
             float* __restrict__ scal) {
  int tid = threadIdx.x;

  if (blockIdx.x == 32) {
    double rz = 0.0, rz2 = 0.0, rv = 0.0;
    for (int i = tid; i < nblocks; i += 256) {
      const double* p = partials + (size_t)i * 4;
      rz += p[0]; rz2 += p[1]; rv += p[2];
    }
#pragma unroll
    for (int off = 32; off > 0; off >>= 1) {
      rz  += __shfl_down(rz,  off, 64);
      rz2 += __shfl_down(rz2, off, 64);
      rv  += __shfl_down(rv,  off, 64);
    }
    __shared__ double s[3][4];
    if ((tid & 63) == 0) {
      int w = tid >> 6;
      s[0][w] = rz; s[1][w] = rz2; s[2][w] = rv;
    }
    __syncthreads();
    if (tid == 0) {
      double sz = 0, sz2 = 0, nv = 0;
#pragma unroll
      for (int w = 0; w < 4; ++w) { sz += s[0][w]; sz2 += s[1][w]; nv += s[2][w]; }
      double nvm = (nv > 1.0) ? nv : 1.0;
      double zmean = sz / nvm;
      double var = sz2 - 2.0 * zmean * sz + zmean * zmean * nv;
      if (var < 0.0) var = 0.0;
      scal[0] = (float)zmean;
      scal[1] = (float)(sqrt(var) + 1e-5);
    }
    return;
  }

  // chunk b = bins [b*1024, b*1024+1024): 256 threads x 1 int4
  __shared__ int red[256];
  int4 h = ((const int4*)hist)[blockIdx.x * 256 + tid];
  red[tid] = h.x + h.y + h.z + h.w;
  __syncthreads();
  for (int off = 128; off > 0; off >>= 1) {
    if (tid < off) red[tid] += red[tid + off];
    __syncthreads();
  }
  if (tid == 0) bsum[blockIdx.x] = red[0];
}

// scanB: 32 blocks; each computes its global base from bsum (32 entries),
// then locally scans its 1024 bins and writes exclusive offsets.
__global__ __launch_bounds__(256)
void scanB_k(const int* __restrict__ hist, const int* __restrict__ bsum,
             int* __restrict__ ofs) {
  __shared__ int sb[32];
  __shared__ int st[256];
  int tid = threadIdx.x;

  if (tid < 32) sb[tid] = bsum[tid];
  __syncthreads();
  if (tid == 0) {   // exclusive scan of 32 chunk sums (trivial)
    int acc = 0;
    for (int i = 0; i < 32; ++i) { int t = sb[i]; sb[i] = acc; acc += t; }
  }
  __syncthreads();
  int base_blk = sb[blockIdx.x];

  int idx = blockIdx.x * 256 + tid;
  int4 h = ((const int4*)hist)[idx];
  int tsum = h.x + h.y + h.z + h.w;
  st[tid] = tsum;
  __syncthreads();
  for (int off = 1; off < 256; off <<= 1) {
    int v = (tid >= off) ? st[tid - off] : 0;
    __syncthreads();
    st[tid] += v;
    __syncthreads();
  }
  int base = base_blk + st[tid] - tsum;  // exclusive thread prefix
  int4 o;
  o.x = base;
  o.y = base + h.x;
  o.z = o.y + h.y;
  o.w = o.z + h.z;
  ((int4*)ofs)[idx] = o;
}

// pure scatter: packed records (x | y<<7 | z<<14, n)
__global__ __launch_bounds__(256)
void scatter_k(const int4* __restrict__ coords, int* __restrict__ ofs,
               int2* __restrict__ sorted, int N) {
  int n = blockIdx.x * blockDim.x + threadIdx.x;
  if (n >= N) return;
  int4 cd = coords[n];
  int pos = atomicAdd(&ofs[voxel_key(cd)], 1);
  sorted[pos] = make_int2(cd.y | (cd.z << 7) | (cd.w << 14), n);
}

// Main gather: 3 waves x 64 voxels. Phase A: wave p projects views 3p..3p+2
// for its 64 voxels into LDS (offset + dx/dy + half2-broadcast weights).
// Phase B: every wave consumes all 9 views for its channel plane, SKIPPING
// views whose weights are all zero (wave-coherent after morton sort).
__global__ __launch_bounds__(192, 4)
void bp_gather_k(const int2* __restrict__ sorted, const float* __restrict__ origin,
                 const float* __restrict__ proj, const __half* __restrict__ featsT,
                 const float* __restrict__ scal, float* __restrict__ out, int N) {
  __shared__ float s_proj[NV * 12];
  __shared__ float s_org[3];
  __shared__ float s_scal[2];
  __shared__ uint2 s_offd[NV][64];   // {byte offset, dx | (dy<<16)}
  __shared__ uint4 s_w2[NV][64];     // 4 broadcast-half2 weights
  __shared__ float s_zs[3][64];
  __shared__ int   s_cnt[3][64];
  int tid = threadIdx.x;
  if (tid < NV * 12) s_proj[tid] = proj[(tid / 12) * 16 + (tid % 12)];
  if (tid < 3) s_org[tid] = origin[tid];
  if (tid < 2) s_scal[tid] = scal[tid];
  __syncthreads();

  int nwg = gridDim.x, orig = blockIdx.x;
  int xcd = orig & 7, q = nwg >> 3, r = nwg & 7;
  int bid = (xcd < r ? xcd * (q + 1) : r * (q + 1) + (xcd - r) * q) + (orig >> 3);

  int lane = tid & 63, part = tid >> 6;
  int i = bid * 64 + lane;
  int n = -1, xi = 0, yi = 0, zi = 0;
  if (i < N) {
    int2 rec = sorted[i];
    n = rec.y;
    xi = rec.x & 127; yi = (rec.x >> 7) & 127; zi = (rec.x >> 14) & 127;
  }
  float wx = (float)xi * VOXSZ + s_org[0];
  float wy = (float)yi * VOXSZ + s_org[1];
  float wz = (float)zi * VOXSZ + s_org[2];
  float vm = (n >= 0) ? 1.f : 0.f;

  // ---- phase A: produce projection data for views 3*part .. 3*part+2 ----
  float zsp = 0.f; int cntp = 0;
#pragma unroll
  for (int qv = 0; qv < 3; ++qv) {
    int v = 3 * part + qv;
    const float* P = &s_proj[v * 12];
    float ix = P[0] * wx + P[1] * wy + P[2]  * wz + P[3];
    float iy = P[4] * wx + P[5] * wy + P[6]  * wz + P[7];
    float iz = P[8] * wx + P[9] * wy + P[10] * wz + P[11];
    float px = ix / iz, py = iy / iz;
    bool inb = (px >= 0.f) && (px <= (float)(NW - 1)) &&
               (py >= 0.f) && (py <= (float)(NH - 1)) && (iz > 0.f);
    float wm = inb ? vm : 0.f;
    cntp += (wm > 0.f) ? 1 : 0;
    zsp = fmaf(wm, iz, zsp);
    float pxc = fminf(fmaxf(px, 0.f), (float)(NW - 1));
    float pyc = fminf(fmaxf(py, 0.f), (float)(NH - 1));
    float x0f = floorf(pxc), y0f = floorf(pyc);
    float fx1 = pxc - x0f, fy1 = pyc - y0f;
    float fx0 = 1.f - fx1, fy0 = 1.f - fy1;
    int x0 = (int)x0f, y0 = (int)y0f;
    // x1==NW (y1==NH) only when weight is exactly 0 -> dx=0 reuse is exact
    unsigned dx = (x0 + 1 < NW) ? 16u : 0u;
    unsigned dy = (y0 + 1 < NH) ? (unsigned)(NW * 16) : 0u;
    unsigned off = (unsigned)(((y0 + v * NH) * NW + x0) * 16);
    // weights sum to wm -> all-zero half2 weights  <=>  wm == 0
    __half2 h00 = __float2half2_rn(fx0 * fy0 * wm);
    __half2 h10 = __float2half2_rn(fx1 * fy0 * wm);
    __half2 h01 = __float2half2_rn(fx0 * fy1 * wm);
    __half2 h11 = __float2half2_rn(fx1 * fy1 * wm);
    s_offd[v][lane] = make_uint2(off, dx | (dy << 16));
    uint4 wv;
    wv.x = *(unsigned int*)&h00;
    wv.y = *(unsigned int*)&h10;
    wv.z = *(unsigned int*)&h01;
    wv.w = *(unsigned int*)&h11;
    s_w2[v][lane] = wv;
  }
  s_zs[part][lane] = zsp;
  s_cnt[part][lane] = cntp;
  __syncthreads();

  // ---- phase B: consume views (skip zero-weight ones, wave-coherent) ----
  int cnt = s_cnt[0][lane] + s_cnt[1][lane] + s_cnt[2][lane];
  __half2 acc2[4];
  const __half2 zero2 = __float2half2_rn(0.f);
#pragma unroll
  for (int c = 0; c < 4; ++c) acc2[c] = zero2;
  const char* fbase = (const char*)featsT + (size_t)part * PLANE_BYTES;

#pragma unroll
  for (int v = 0; v < NV; ++v) {
    uint4 wv = s_w2[v][lane];
    if ((wv.x | wv.y | wv.z | wv.w) == 0u) continue;   // out-of-bounds view
    uint2 od = s_offd[v][lane];
    unsigned dx = od.y & 0xFFFFu, dy = od.y >> 16;
    const char* p00 = fbase + od.x;
    float4 c00 = *(const float4*)p00;
    float4 c10 = *(const float4*)(p00 + dx);
    float4 c01 = *(const float4*)(p00 + dy);
    float4 c11 = *(const float4*)(p00 + dx + dy);
    __half2 w00 = *(__half2*)&wv.x;
    __half2 w10 = *(__half2*)&wv.y;
    __half2 w01 = *(__half2*)&wv.z;
    __half2 w11 = *(__half2*)&wv.w;
    const __half2* h00 = (const __half2*)&c00;
    const __half2* h10 = (const __half2*)&c10;
    const __half2* h01 = (const __half2*)&c01;
    const __half2* h11 = (const __half2*)&c11;
#pragma unroll
    for (int c = 0; c < 4; ++c) acc2[c] = __hfma2(w00, h00[c], acc2[c]);
#pragma unroll
    for (int c = 0; c < 4; ++c) acc2[c] = __hfma2(w10, h10[c], acc2[c]);
#pragma unroll
    for (int c = 0; c < 4; ++c) acc2[c] = __hfma2(w01, h01[c], acc2[c]);
#pragma unroll
    for (int c = 0; c < 4; ++c) acc2[c] = __hfma2(w11, h11[c], acc2[c]);
  }

  if (n < 0) return;
  float denom = (cnt > 0) ? (float)cnt : 1.f;
  float inv = 1.f / denom;
  size_t row = (size_t)n * (NC + 1) + part * 8;
#pragma unroll
  for (int c = 0; c < 4; ++c) {
    float2 t = __half22float2(acc2[c]);
    out[row + 2 * c]     = t.x * inv;
    out[row + 2 * c + 1] = t.y * inv;
  }
  if (part == 2) {
    float zs = s_zs[0][lane] + s_zs[1][lane] + s_zs[2][lane];
    float zsv = zs * inv;
    out[(size_t)n * (NC + 1) + NC] = (cnt > 0) ? (zsv - s_scal[0]) / s_scal[1] : 0.f;
  }
  // count is written coalesced by prep_k
}

// ---- fallback path (ws too small): projection stats + direct f32 gather ----
__global__ __launch_bounds__(256)
void stats_k(const int4* __restrict__ coords, const float* __restrict__ origin,
             const float* __restrict__ proj, double* __restrict__ partials, int N) {
  __shared__ float s_proj[NV * 12];
  __shared__ float s_org[3];
  __shared__ double s_red[3][4];
  int tid = threadIdx.x;
  if (tid < NV * 12) s_proj[tid] = proj[(tid / 12) * 16 + (tid % 12)];
  if (tid < 3) s_org[tid] = origin[tid];
  __syncthreads();
  int n = blockIdx.x * blockDim.x + tid;
  double rz = 0.0, rz2 = 0.0, rv = 0.0;
  if (n < N) {
    int4 cd = coords[n];
    float wx = (float)cd.y * VOXSZ + s_org[0];
    float wy = (float)cd.z * VOXSZ + s_org[1];
    float wz = (float)cd.w * VOXSZ + s_org[2];
    float zs = 0.f; int cnt = 0;
#pragma unroll
    for (int v = 0; v < NV; ++v) {
      const float* P = &s_proj[v * 12];
      float ix = P[0] * wx + P[1] * wy + P[2]  * wz + P[3];
      float iy = P[4] * wx + P[5] * wy + P[6]  * wz + P[7];
      float iz = P[8] * wx + P[9] * wy + P[10] * wz + P[11];
      float px = ix / iz, py = iy / iz;
      bool inb = (px >= 0.f) && (px <= (float)(NW - 1)) &&
                 (py >= 0.f) && (py <= (float)(NH - 1)) && (iz > 0.f);
      if (inb) { cnt++; zs += iz; }
    }
    if (cnt > 0) {
      float zsv = zs / (float)cnt;
      rz = (double)zsv; rz2 = (double)zsv * (double)zsv; rv = 1.0;
    }
  }
#pragma unroll
  for (int off = 32; off > 0; off >>= 1) {
    rz  += __shfl_down(rz,  off, 64);
    rz2 += __shfl_down(rz2, off, 64);
    rv  += __shfl_down(rv,  off, 64);
  }
  if ((tid & 63) == 0) {
    int w = tid >> 6;
    s_red[0][w] = rz; s_red[1][w] = rz2; s_red[2][w] = rv;
  }
  __syncthreads();
  if (tid == 0) {
    double a = 0, b = 0, c = 0;
#pragma unroll
    for (int w = 0; w < 4; ++w) { a += s_red[0][w]; b += s_red[1][w]; c += s_red[2][w]; }
    double* p = partials + (size_t)blockIdx.x * 4;
    p[0] = a; p[1] = b; p[2] = c;
  }
}

__global__ __launch_bounds__(1024)
void reduce_finalize_k(const double* __restrict__ partials, int nblocks,
                       float* __restrict__ scal) {
  int tid = threadIdx.x;
  double rz = 0.0, rz2 = 0.0, rv = 0.0;
  for (int i = tid; i < nblocks; i += 1024) {
    const double* p = partials + (size_t)i * 4;
    rz += p[0]; rz2 += p[1]; rv += p[2];
  }
#pragma unroll
  for (int off = 32; off > 0; off >>= 1) {
    rz  += __shfl_down(rz,  off, 64);
    rz2 += __shfl_down(rz2, off, 64);
    rv  += __shfl_down(rv,  off, 64);
  }
  __shared__ double s[3][16];
  if ((tid & 63) == 0) {
    int w = tid >> 6;
    s[0][w] = rz; s[1][w] = rz2; s[2][w] = rv;
  }
  __syncthreads();
  if (tid == 0) {
    double sz = 0, sz2 = 0, nv = 0;
#pragma unroll
    for (int w = 0; w < 16; ++w) { sz += s[0][w]; sz2 += s[1][w]; nv += s[2][w]; }
    double nvm = (nv > 1.0) ? nv : 1.0;
    double zmean = sz / nvm;
    double var = sz2 - 2.0 * zmean * sz + zmean * zmean * nv;
    if (var < 0.0) var = 0.0;
    scal[0] = (float)zmean;
    scal[1] = (float)(sqrt(var) + 1e-5);
  }
}

__global__ __launch_bounds__(256)
void bp_fallback_k(const int4* __restrict__ coords, const float* __restrict__ origin,
                   const float* __restrict__ proj, const float* __restrict__ feats,
                   const float* __restrict__ scal, float* __restrict__ out, int N) {
  __shared__ float s_proj[NV * 12];
  __shared__ float s_org[3];
  __shared__ float s_scal[2];
  int tid = threadIdx.x;
  if (tid < NV * 12) s_proj[tid] = proj[(tid / 12) * 16 + (tid % 12)];
  if (tid < 3) s_org[tid] = origin[tid];
  if (tid < 2) s_scal[tid] = scal[tid];
  __syncthreads();
  int n = blockIdx.x * blockDim.x + tid;
  if (n >= N) return;
  int4 cd = coords[n];
  float wx = (float)cd.y * VOXSZ + s_org[0];
  float wy = (float)cd.z * VOXSZ + s_org[1];
  float wz = (float)cd.w * VOXSZ + s_org[2];
  float acc[NC];
#pragma unroll
  for (int c = 0; c < NC; ++c) acc[c] = 0.f;
  float zs = 0.f; int cnt = 0;
#pragma unroll
  for (int v = 0; v < NV; ++v) {
    const float* P = &s_proj[v * 12];
    float ix = P[0] * wx + P[1] * wy + P[2]  * wz + P[3];
    float iy = P[4] * wx + P[5] * wy + P[6]  * wz + P[7];
    float iz = P[8] * wx + P[9] * wy + P[10] * wz + P[11];
    float px = ix / iz, py = iy / iz;
    bool inb = (px >= 0.f) && (px <= (float)(NW - 1)) &&
               (py >= 0.f) && (py <= (float)(NH - 1)) && (iz > 0.f);
    if (!inb) continue;
    cnt++; zs += iz;
    float x0f = floorf(px), y0f = floorf(py);
    float fx1 = px - x0f, fy1 = py - y0f;
    float fx0 = 1.f - fx1, fy0 = 1.f - fy1;
    int x0 = (int)x0f, y0 = (int)y0f;
    int x1 = (x0 + 1 < NW) ? x0 + 1 : NW - 1;
    int y1 = (y0 + 1 < NH) ? y0 + 1 : NH - 1;
    float w00 = fx0 * fy0, w10 = fx1 * fy0, w01 = fx0 * fy1, w11 = fx1 * fy1;
    const float* base = feats + (size_t)v * NC * NH * NW;
#pragma unroll
    for (int c = 0; c < NC; ++c) {
      const float* pc = base + (size_t)c * NH * NW;
      acc[c] += pc[y0 * NW + x0] * w00 + pc[y0 * NW + x1] * w10 +
                pc[y1 * NW + x0] * w01 + pc[y1 * NW + x1] * w11;
    }
  }
  float denom = (cnt > 0) ? (float)cnt : 1.f;
  float inv = 1.f / denom;
  size_t row = (size_t)n * (NC + 1);
#pragma unroll
  for (int c = 0; c < NC; ++c) out[row + c] = acc[c] * inv;
  float zsv = zs * inv;
  out[row + NC] = (cnt > 0) ? (zsv - s_scal[0]) / s_scal[1] : 0.f;
  out[(size_t)N * (NC + 1) + n] = (float)cnt;
}

extern "C" void kernel_launch(void* const* d_in, const int* in_sizes, int n_in,
                              void* d_out, int out_size, void* d_ws, size_t ws_size,
                              hipStream_t stream) {
  const int4*  coords = (const int4*)d_in[0];
  const float* origin = (const float*)d_in[1];
  const float* feats  = (const float*)d_in[2];
  const float* proj   = (const float*)d_in[3];
  float* out = (float*)d_out;
  int N = in_sizes[0] / 4;

  int blocksAll = (N + 255) / 256;

  char* ws = (char*)d_ws;
  float*  scal     = (float*)ws;                 // 2 floats
  double* partials = (double*)(ws + 64);
  size_t off = 64 + (size_t)blocksAll * 4 * sizeof(double);
  off = (off + 63) & ~(size_t)63;
  __half* featsT = (__half*)(ws + off);
  off += 3 * PLANE_BYTES;                        // 3 planes of 16 B/pixel
  int* hist = (int*)(ws + off); off += (size_t)NBINS * sizeof(int);
  int* ofs  = (int*)(ws + off); off += (size_t)NBINS * sizeof(int);
  int* bsum = (int*)(ws + off); off += 64 * sizeof(int);
  off = (off + 15) & ~(size_t)15;
  int2* sorted = (int2*)(ws + off); off += (size_t)N * sizeof(int2);
  bool full = (ws_size >= off);

  if (full) {
    zero_hist_k<<<NBINS / 1024, 256, 0, stream>>>((int4*)hist);
    prep_k<<<TBLOCKS + blocksAll, 256, 0, stream>>>(feats, featsT, coords, origin,
                                                    proj, hist, partials, out, N);
    scanA_k<<<33, 256, 0, stream>>>(hist, bsum, partials, blocksAll, scal);
    scanB_k<<<32, 256, 0, stream>>>(hist, bsum, ofs);
    scatter_k<<<blocksAll, 256, 0, stream>>>(coords, ofs, sorted, N);
    int gblocks = (N + 63) / 64;
    bp_gather_k<<<gblocks, 192, 0, stream>>>(sorted, origin, proj, featsT, scal, out, N);
  } else {
    stats_k<<<blocksAll, 256, 0, stream>>>(coords, origin, proj, partials, N);
    reduce_finalize_k<<<1, 1024, 0, stream>>>(partials, blocksAll, scal);
    bp_fallback_k<<<blocksAll, 256, 0, stream>>>(coords, origin, proj, feats, scal, out, N);
  }
}

// Round 15
// 82.300 us; speedup vs baseline: 3.4548x; 1.0451x over previous
//
#include <hip/hip_runtime.h>
#include <hip/hip_fp16.h>
#include <math.h>

#define VOXSZ 0.04f
#define NV 9
#define NC 24
#define NH 120
#define NW 160
#define NBINS 262144        // 18-bit full-resolution morton key
#define TBLOCKS (NV * NH)   // 1080 transpose blocks in prep_k
#define PLANE_BYTES ((size_t)NV * NH * NW * 16)  // 16 B/pixel per plane

// ---------------------------------------------------------------------------
// ws layout:
//   [0,64):  2 f32 scalars (zmean, zstd)
//   [64,+):  per-block partials (4 doubles each)
//   then:    featsT fp16 as 3 planes of 16 B/pixel (plane p = ch 8p..8p+7),
//            hist[NBINS], ofs[NBINS], bsum[256], sorted[N] int2
// ---------------------------------------------------------------------------

__device__ __forceinline__ int morton6(int a) {   // 6 bits -> every 3rd bit
  a = (a | (a << 8)) & 0x300F;
  a = (a | (a << 4)) & 0x30C3;
  a = (a | (a << 2)) & 0x9249;
  return a;
}

__device__ __forceinline__ int voxel_key(int4 cd) {
  // clamp 64->63: key need not be injective, only spatially local
  int x = min(max(cd.y, 0), 63), y = min(max(cd.z, 0), 63), z = min(max(cd.w, 0), 63);
  return morton6(x) | (morton6(y) << 1) | (morton6(z) << 2);
}

// full-BW hist clear: 256 blocks x 256 threads x int4 = 1 MB
__global__ __launch_bounds__(256)
void zero_hist_k(int4* __restrict__ hist4) {
  hist4[blockIdx.x * 256 + threadIdx.x] = make_int4(0, 0, 0, 0);
}

// Fused prep: blocks [0,TBLOCKS) transpose feats; rest do hist + stats +
// coalesced per-voxel count output (count only depends on projections).
__global__ __launch_bounds__(256)
void prep_k(const float* __restrict__ feats, __half* __restrict__ outT,
            const int4* __restrict__ coords, const float* __restrict__ origin,
            const float* __restrict__ proj, int* __restrict__ hist,
            double* __restrict__ partials, float* __restrict__ out, int N) {
  __shared__ __half s[NC][NW + 2];
  __shared__ float s_proj[NV * 12];
  __shared__ float s_org[3];
  __shared__ double s_red[3][4];
  int tid = threadIdx.x;

  if (blockIdx.x < TBLOCKS) {
    // --- transpose role: f32 (V,C,H,W) -> 3 fp16 planes (V,H,W,8ch) ---
    int vh = blockIdx.x;
    int v = vh / NH, h = vh % NH;
    const float* ibase = feats + (size_t)v * NC * NH * NW + (size_t)h * NW;
    for (int e = tid; e < NC * (NW / 4); e += 256) {
      int c = e / (NW / 4), w4 = e - c * (NW / 4);
      float4 f = *(const float4*)(ibase + (size_t)c * NH * NW + w4 * 4);
      int w = w4 * 4;
      s[c][w]     = __float2half(f.x);
      s[c][w + 1] = __float2half(f.y);
      s[c][w + 2] = __float2half(f.z);
      s[c][w + 3] = __float2half(f.w);
    }
    __syncthreads();
    for (int j = tid; j < NW * 12; j += 256) {
      int p = j / (NW * 4);
      int rem = j - p * (NW * 4);
      int w = rem >> 2, k = rem & 3;
      __half2 hv = __halves2half2(s[8 * p + 2 * k][w], s[8 * p + 2 * k + 1][w]);
      unsigned int* obase =
          (unsigned int*)((char*)outT + (size_t)p * PLANE_BYTES) + (size_t)vh * NW * 4;
      obase[(w << 2) | k] = *(unsigned int*)&hv;
    }
    return;
  }

  // --- hist + stats + count role ---
  if (tid < NV * 12) s_proj[tid] = proj[(tid / 12) * 16 + (tid % 12)];
  if (tid < 3) s_org[tid] = origin[tid];
  __syncthreads();

  int sid = blockIdx.x - TBLOCKS;
  int n = sid * 256 + tid;
  double rz = 0.0, rz2 = 0.0, rv = 0.0;
  if (n < N) {
    int4 cd = coords[n];
    atomicAdd(&hist[voxel_key(cd)], 1);
    float wx = (float)cd.y * VOXSZ + s_org[0];
    float wy = (float)cd.z * VOXSZ + s_org[1];
    float wz = (float)cd.w * VOXSZ + s_org[2];
    float zs = 0.f; int cnt = 0;
#pragma unroll
    for (int v = 0; v < NV; ++v) {
      const float* P = &s_proj[v * 12];
      float ix = P[0] * wx + P[1] * wy + P[2]  * wz + P[3];
      float iy = P[4] * wx + P[5] * wy + P[6]  * wz + P[7];
      float iz = P[8] * wx + P[9] * wy + P[10] * wz + P[11];
      float px = ix / iz, py = iy / iz;
      bool inb = (px >= 0.f) && (px <= (float)(NW - 1)) &&
                 (py >= 0.f) && (py <= (float)(NH - 1)) && (iz > 0.f);
      if (inb) { cnt++; zs += iz; }
    }
    out[(size_t)N * (NC + 1) + n] = (float)cnt;   // coalesced count output
    if (cnt > 0) {
      float zsv = zs / (float)cnt;
      rz = (double)zsv; rz2 = (double)zsv * (double)zsv; rv = 1.0;
    }
  }
#pragma unroll
  for (int off = 32; off > 0; off >>= 1) {
    rz  += __shfl_down(rz,  off, 64);
    rz2 += __shfl_down(rz2, off, 64);
    rv  += __shfl_down(rv,  off, 64);
  }
  if ((tid & 63) == 0) {
    int w = tid >> 6;
    s_red[0][w] = rz; s_red[1][w] = rz2; s_red[2][w] = rv;
  }
  __syncthreads();
  if (tid == 0) {
    double a = 0, b = 0, c = 0;
#pragma unroll
    for (int w = 0; w < 4; ++w) { a += s_red[0][w]; b += s_red[1][w]; c += s_red[2][w]; }
    double* p = partials + (size_t)sid * 4;
    p[0] = a; p[1] = b; p[2] = c;
  }
}

// scanA: blocks 0..255 reduce 1024 bins each -> bsum[b]; block 256 finalizes stats
__global__ __launch_bounds__(256)
void scanA_k(const int* __restrict__ hist, int* __restrict__ bsum,
             const double* __restrict__ partials, int nblocks,
             float* __restrict__ scal) {
  int tid = threadIdx.x;

  if (blockIdx.x == 256) {
    double rz = 0.0, rz2 = 0.0, rv = 0.0;
    for (int i = tid; i < nblocks; i += 256) {
      const double* p = partials + (size_t)i * 4;
      rz += p[0]; rz2 += p[1]; rv += p[2];
    }
#pragma unroll
    for (int off = 32; off > 0; off >>= 1) {
      rz  += __shfl_down(rz,  off, 64);
      rz2 += __shfl_down(rz2, off, 64);
      rv  += __shfl_down(rv,  off, 64);
    }
    __shared__ double s[3][4];
    if ((tid & 63) == 0) {
      int w = tid >> 6;
      s[0][w] = rz; s[1][w] = rz2; s[2][w] = rv;
    }
    __syncthreads();
    if (tid == 0) {
      double sz = 0, sz2 = 0, nv = 0;
#pragma unroll
      for (int w = 0; w < 4; ++w) { sz += s[0][w]; sz2 += s[1][w]; nv += s[2][w]; }
      double nvm = (nv > 1.0) ? nv : 1.0;
      double zmean = sz / nvm;
      double var = sz2 - 2.0 * zmean * sz + zmean * zmean * nv;
      if (var < 0.0) var = 0.0;
      scal[0] = (float)zmean;
      scal[1] = (float)(sqrt(var) + 1e-5);
    }
    return;
  }

  __shared__ int red[256];
  int4 h = ((const int4*)hist)[blockIdx.x * 256 + tid];
  red[tid] = h.x + h.y + h.z + h.w;
  __syncthreads();
  for (int off = 128; off > 0; off >>= 1) {
    if (tid < off) red[tid] += red[tid + off];
    __syncthreads();
  }
  if (tid == 0) bsum[blockIdx.x] = red[0];
}

// scanB: each block computes its global base from bsum, then locally scans
// its 1024 bins and writes exclusive offsets.
__global__ __launch_bounds__(256)
void scanB_k(const int* __restrict__ hist, const int* __restrict__ bsum,
             int* __restrict__ ofs) {
  __shared__ int sb[256];
  __shared__ int st[256];
  int tid = threadIdx.x;

  sb[tid] = bsum[tid];
  __syncthreads();
  for (int off = 1; off < 256; off <<= 1) {
    int v = (tid >= off) ? sb[tid - off] : 0;
    __syncthreads();
    sb[tid] += v;
    __syncthreads();
  }
  int base_blk = (blockIdx.x == 0) ? 0 : sb[blockIdx.x - 1];

  int idx = blockIdx.x * 256 + tid;
  int4 h = ((const int4*)hist)[idx];
  int tsum = h.x + h.y + h.z + h.w;
  st[tid] = tsum;
  __syncthreads();
  for (int off = 1; off < 256; off <<= 1) {
    int v = (tid >= off) ? st[tid - off] : 0;
    __syncthreads();
    st[tid] += v;
    __syncthreads();
  }
  int base = base_blk + st[tid] - tsum;  // exclusive thread prefix
  int4 o;
  o.x = base;
  o.y = base + h.x;
  o.z = o.y + h.y;
  o.w = o.z + h.z;
  ((int4*)ofs)[idx] = o;
}

// pure scatter: packed records (x | y<<7 | z<<14, n)
__global__ __launch_bounds__(256)
void scatter_k(const int4* __restrict__ coords, int* __restrict__ ofs,
               int2* __restrict__ sorted, int N) {
  int n = blockIdx.x * blockDim.x + threadIdx.x;
  if (n >= N) return;
  int4 cd = coords[n];
  int pos = atomicAdd(&ofs[voxel_key(cd)], 1);
  sorted[pos] = make_int2(cd.y | (cd.z << 7) | (cd.w << 14), n);
}

// Main gather: 3 waves x 64 voxels. Phase A: wave p projects views 3p..3p+2
// for its 64 voxels into LDS (offset + dx/dy + 4 packed half weights, 8 B).
// Phase B: every wave consumes all 9 views for its channel plane, SKIPPING
// views whose weights are all zero (wave-coherent after morton sort).
__global__ __launch_bounds__(192, 4)
void bp_gather_k(const int2* __restrict__ sorted, const float* __restrict__ origin,
                 const float* __restrict__ proj, const __half* __restrict__ featsT,
                 const float* __restrict__ scal, float* __restrict__ out, int N) {
  __shared__ float s_proj[NV * 12];
  __shared__ float s_org[3];
  __shared__ float s_scal[2];
  __shared__ uint2 s_offd[NV][64];   // {byte offset, dx | (dy<<16)}
  __shared__ uint2 s_w2[NV][64];     // 4 packed halfs: {w00,w10}, {w01,w11}
  __shared__ float s_zs[3][64];
  __shared__ int   s_cnt[3][64];
  int tid = threadIdx.x;
  if (tid < NV * 12) s_proj[tid] = proj[(tid / 12) * 16 + (tid % 12)];
  if (tid < 3) s_org[tid] = origin[tid];
  if (tid < 2) s_scal[tid] = scal[tid];
  __syncthreads();

  int nwg = gridDim.x, orig = blockIdx.x;
  int xcd = orig & 7, q = nwg >> 3, r = nwg & 7;
  int bid = (xcd < r ? xcd * (q + 1) : r * (q + 1) + (xcd - r) * q) + (orig >> 3);

  int lane = tid & 63, part = tid >> 6;
  int i = bid * 64 + lane;
  int n = -1, xi = 0, yi = 0, zi = 0;
  if (i < N) {
    int2 rec = sorted[i];
    n = rec.y;
    xi = rec.x & 127; yi = (rec.x >> 7) & 127; zi = (rec.x >> 14) & 127;
  }
  float wx = (float)xi * VOXSZ + s_org[0];
  float wy = (float)yi * VOXSZ + s_org[1];
  float wz = (float)zi * VOXSZ + s_org[2];
  float vm = (n >= 0) ? 1.f : 0.f;

  // ---- phase A: produce projection data for views 3*part .. 3*part+2 ----
  float zsp = 0.f; int cntp = 0;
#pragma unroll
  for (int qv = 0; qv < 3; ++qv) {
    int v = 3 * part + qv;
    const float* P = &s_proj[v * 12];
    float ix = P[0] * wx + P[1] * wy + P[2]  * wz + P[3];
    float iy = P[4] * wx + P[5] * wy + P[6]  * wz + P[7];
    float iz = P[8] * wx + P[9] * wy + P[10] * wz + P[11];
    float px = ix / iz, py = iy / iz;
    bool inb = (px >= 0.f) && (px <= (float)(NW - 1)) &&
               (py >= 0.f) && (py <= (float)(NH - 1)) && (iz > 0.f);
    float wm = inb ? vm : 0.f;
    cntp += (wm > 0.f) ? 1 : 0;
    zsp = fmaf(wm, iz, zsp);
    float pxc = fminf(fmaxf(px, 0.f), (float)(NW - 1));
    float pyc = fminf(fmaxf(py, 0.f), (float)(NH - 1));
    float x0f = floorf(pxc), y0f = floorf(pyc);
    float fx1 = pxc - x0f, fy1 = pyc - y0f;
    float fx0 = 1.f - fx1, fy0 = 1.f - fy1;
    int x0 = (int)x0f, y0 = (int)y0f;
    // x1==NW (y1==NH) only when weight is exactly 0 -> dx=0 reuse is exact
    unsigned dx = (x0 + 1 < NW) ? 16u : 0u;
    unsigned dy = (y0 + 1 < NH) ? (unsigned)(NW * 16) : 0u;
    unsigned off = (unsigned)(((y0 + v * NH) * NW + x0) * 16);
    // weights sum to wm -> all-zero packed weights  <=>  wm == 0
    __half2 p01 = __halves2half2(__float2half(fx0 * fy0 * wm),
                                 __float2half(fx1 * fy0 * wm));
    __half2 p23 = __halves2half2(__float2half(fx0 * fy1 * wm),
                                 __float2half(fx1 * fy1 * wm));
    s_offd[v][lane] = make_uint2(off, dx | (dy << 16));
    s_w2[v][lane] = make_uint2(*(unsigned int*)&p01, *(unsigned int*)&p23);
  }
  s_zs[part][lane] = zsp;
  s_cnt[part][lane] = cntp;
  __syncthreads();

  // ---- phase B: consume views (skip zero-weight ones, wave-coherent) ----
  int cnt = s_cnt[0][lane] + s_cnt[1][lane] + s_cnt[2][lane];
  __half2 acc2[4];
  const __half2 zero2 = __float2half2_rn(0.f);
#pragma unroll
  for (int c = 0; c < 4; ++c) acc2[c] = zero2;
  const char* fbase = (const char*)featsT + (size_t)part * PLANE_BYTES;

#pragma unroll
  for (int v = 0; v < NV; ++v) {
    uint2 wv = s_w2[v][lane];
    if ((wv.x | wv.y) == 0u) continue;   // out-of-bounds view
    uint2 od = s_offd[v][lane];
    unsigned dx = od.y & 0xFFFFu, dy = od.y >> 16;
    const char* p00 = fbase + od.x;
    float4 c00 = *(const float4*)p00;
    float4 c10 = *(const float4*)(p00 + dx);
    float4 c01 = *(const float4*)(p00 + dy);
    float4 c11 = *(const float4*)(p00 + dx + dy);
    __half2 p01 = *(__half2*)&wv.x;
    __half2 p23 = *(__half2*)&wv.y;
    __half2 w00 = __half2half2(__low2half(p01));
    __half2 w10 = __half2half2(__high2half(p01));
    __half2 w01 = __half2half2(__low2half(p23));
    __half2 w11 = __half2half2(__high2half(p23));
    const __half2* h00 = (const __half2*)&c00;
    const __half2* h10 = (const __half2*)&c10;
    const __half2* h01 = (const __half2*)&c01;
    const __half2* h11 = (const __half2*)&c11;
#pragma unroll
    for (int c = 0; c < 4; ++c) acc2[c] = __hfma2(w00, h00[c], acc2[c]);
#pragma unroll
    for (int c = 0; c < 4; ++c) acc2[c] = __hfma2(w10, h10[c], acc2[c]);
#pragma unroll
    for (int c = 0; c < 4; ++c) acc2[c] = __hfma2(w01, h01[c], acc2[c]);
#pragma unroll
    for (int c = 0; c < 4; ++c) acc2[c] = __hfma2(w11, h11[c], acc2[c]);
  }

  if (n < 0) return;
  float denom = (cnt > 0) ? (float)cnt : 1.f;
  float inv = 1.f / denom;
  size_t row = (size_t)n * (NC + 1) + part * 8;
#pragma unroll
  for (int c = 0; c < 4; ++c) {
    float2 t = __half22float2(acc2[c]);
    out[row + 2 * c]     = t.x * inv;
    out[row + 2 * c + 1] = t.y * inv;
  }
  if (part == 2) {
    float zs = s_zs[0][lane] + s_zs[1][lane] + s_zs[2][lane];
    float zsv = zs * inv;
    out[(size_t)n * (NC + 1) + NC] = (cnt > 0) ? (zsv - s_scal[0]) / s_scal[1] : 0.f;
  }
  // count is written coalesced by prep_k
}

// ---- fallback path (ws too small): projection stats + direct f32 gather ----
__global__ __launch_bounds__(256)
void stats_k(const int4* __restrict__ coords, const float* __restrict__ origin,
             const float* __restrict__ proj, double* __restrict__ partials, int N) {
  __shared__ float s_proj[NV * 12];
  __shared__ float s_org[3];
  __shared__ double s_red[3][4];
  int tid = threadIdx.x;
  if (tid < NV * 12) s_proj[tid] = proj[(tid / 12) * 16 + (tid % 12)];
  if (tid < 3) s_org[tid] = origin[tid];
  __syncthreads();
  int n = blockIdx.x * blockDim.x + tid;
  double rz = 0.0, rz2 = 0.0, rv = 0.0;
  if (n < N) {
    int4 cd = coords[n];
    float wx = (float)cd.y * VOXSZ + s_org[0];
    float wy = (float)cd.z * VOXSZ + s_org[1];
    float wz = (float)cd.w * VOXSZ + s_org[2];
    float zs = 0.f; int cnt = 0;
#pragma unroll
    for (int v = 0; v < NV; ++v) {
      const float* P = &s_proj[v * 12];
      float ix = P[0] * wx + P[1] * wy + P[2]  * wz + P[3];
      float iy = P[4] * wx + P[5] * wy + P[6]  * wz + P[7];
      float iz = P[8] * wx + P[9] * wy + P[10] * wz + P[11];
      float px = ix / iz, py = iy / iz;
      bool inb = (px >= 0.f) && (px <= (float)(NW - 1)) &&
                 (py >= 0.f) && (py <= (float)(NH - 1)) && (iz > 0.f);
      if (inb) { cnt++; zs += iz; }
    }
    if (cnt > 0) {
      float zsv = zs / (float)cnt;
      rz = (double)zsv; rz2 = (double)zsv * (double)zsv; rv = 1.0;
    }
  }
#pragma unroll
  for (int off = 32; off > 0; off >>= 1) {
    rz  += __shfl_down(rz,  off, 64);
    rz2 += __shfl_down(rz2, off, 64);
    rv  += __shfl_down(rv,  off, 64);
  }
  if ((tid & 63) == 0) {
    int w = tid >> 6;
    s_red[0][w] = rz; s_red[1][w] = rz2; s_red[2][w] = rv;
  }
  __syncthreads();
  if (tid == 0) {
    double a = 0, b = 0, c = 0;
#pragma unroll
    for (int w = 0; w < 4; ++w) { a += s_red[0][w]; b += s_red[1][w]; c += s_red[2][w]; }
    double* p = partials + (size_t)blockIdx.x * 4;
    p[0] = a; p[1] = b; p[2] = c;
  }
}

__global__ __launch_bounds__(1024)
void reduce_finalize_k(const double* __restrict__ partials, int nblocks,
                       float* __restrict__ scal) {
  int tid = threadIdx.x;
  double rz = 0.0, rz2 = 0.0, rv = 0.0;
  for (int i = tid; i < nblocks; i += 1024) {
    const double* p = partials + (size_t)i * 4;
    rz += p[0]; rz2 += p[1]; rv += p[2];
  }
#pragma unroll
  for (int off = 32; off > 0; off >>= 1) {
    rz  += __shfl_down(rz,  off, 64);
    rz2 += __shfl_down(rz2, off, 64);
    rv  += __shfl_down(rv,  off, 64);
  }
  __shared__ double s[3][16];
  if ((tid & 63) == 0) {
    int w = tid >> 6;
    s[0][w] = rz; s[1][w] = rz2; s[2][w] = rv;
  }
  __syncthreads();
  if (tid == 0) {
    double sz = 0, sz2 = 0, nv = 0;
#pragma unroll
    for (int w = 0; w < 16; ++w) { sz += s[0][w]; sz2 += s[1][w]; nv += s[2][w]; }
    double nvm = (nv > 1.0) ? nv : 1.0;
    double zmean = sz / nvm;
    double var = sz2 - 2.0 * zmean * sz + zmean * zmean * nv;
    if (var < 0.0) var = 0.0;
    scal[0] = (float)zmean;
    scal[1] = (float)(sqrt(var) + 1e-5);
  }
}

__global__ __launch_bounds__(256)
void bp_fallback_k(const int4* __restrict__ coords, const float* __restrict__ origin,
                   const float* __restrict__ proj, const float* __restrict__ feats,
                   const float* __restrict__ scal, float* __restrict__ out, int N) {
  __shared__ float s_proj[NV * 12];
  __shared__ float s_org[3];
  __shared__ float s_scal[2];
  int tid = threadIdx.x;
  if (tid < NV * 12) s_proj[tid] = proj[(tid / 12) * 16 + (tid % 12)];
  if (tid < 3) s_org[tid] = origin[tid];
  if (tid < 2) s_scal[tid] = scal[tid];
  __syncthreads();
  int n = blockIdx.x * blockDim.x + tid;
  if (n >= N) return;
  int4 cd = coords[n];
  float wx = (float)cd.y * VOXSZ + s_org[0];
  float wy = (float)cd.z * VOXSZ + s_org[1];
  float wz = (float)cd.w * VOXSZ + s_org[2];
  float acc[NC];
#pragma unroll
  for (int c = 0; c < NC; ++c) acc[c] = 0.f;
  float zs = 0.f; int cnt = 0;
#pragma unroll
  for (int v = 0; v < NV; ++v) {
    const float* P = &s_proj[v * 12];
    float ix = P[0] * wx + P[1] * wy + P[2]  * wz + P[3];
    float iy = P[4] * wx + P[5] * wy + P[6]  * wz + P[7];
    float iz = P[8] * wx + P[9] * wy + P[10] * wz + P[11];
    float px = ix / iz, py = iy / iz;
    bool inb = (px >= 0.f) && (px <= (float)(NW - 1)) &&
               (py >= 0.f) && (py <= (float)(NH - 1)) && (iz > 0.f);
    if (!inb) continue;
    cnt++; zs += iz;
    float x0f = floorf(px), y0f = floorf(py);
    float fx1 = px - x0f, fy1 = py - y0f;
    float fx0 = 1.f - fx1, fy0 = 1.f - fy1;
    int x0 = (int)x0f, y0 = (int)y0f;
    int x1 = (x0 + 1 < NW) ? x0 + 1 : NW - 1;
    int y1 = (y0 + 1 < NH) ? y0 + 1 : NH - 1;
    float w00 = fx0 * fy0, w10 = fx1 * fy0, w01 = fx0 * fy1, w11 = fx1 * fy1;
    const float* base = feats + (size_t)v * NC * NH * NW;
#pragma unroll
    for (int c = 0; c < NC; ++c) {
      const float* pc = base + (size_t)c * NH * NW;
      acc[c] += pc[y0 * NW + x0] * w00 + pc[y0 * NW + x1] * w10 +
                pc[y1 * NW + x0] * w01 + pc[y1 * NW + x1] * w11;
    }
  }
  float denom = (cnt > 0) ? (float)cnt : 1.f;
  float inv = 1.f / denom;
  size_t row = (size_t)n * (NC + 1);
#pragma unroll
  for (int c = 0; c < NC; ++c) out[row + c] = acc[c] * inv;
  float zsv = zs * inv;
  out[row + NC] = (cnt > 0) ? (zsv - s_scal[0]) / s_scal[1] : 0.f;
  out[(size_t)N * (NC + 1) + n] = (float)cnt;
}

extern "C" void kernel_launch(void* const* d_in, const int* in_sizes, int n_in,
                              void* d_out, int out_size, void* d_ws, size_t ws_size,
                              hipStream_t stream) {
  const int4*  coords = (const int4*)d_in[0];
  const float* origin = (const float*)d_in[1];
  const float* feats  = (const float*)d_in[2];
  const float* proj   = (const float*)d_in[3];
  float* out = (float*)d_out;
  int N = in_sizes[0] / 4;

  int blocksAll = (N + 255) / 256;

  char* ws = (char*)d_ws;
  float*  scal     = (float*)ws;                 // 2 floats
  double* partials = (double*)(ws + 64);
  size_t off = 64 + (size_t)blocksAll * 4 * sizeof(double);
  off = (off + 63) & ~(size_t)63;
  __half* featsT = (__half*)(ws + off);
  off += 3 * PLANE_BYTES;                        // 3 planes of 16 B/pixel
  int* hist = (int*)(ws + off); off += (size_t)NBINS * sizeof(int);
  int* ofs  = (int*)(ws + off); off += (size_t)NBINS * sizeof(int);
  int* bsum = (int*)(ws + off); off += 256 * sizeof(int);
  off = (off + 15) & ~(size_t)15;
  int2* sorted = (int2*)(ws + off); off += (size_t)N * sizeof(int2);
  bool full = (ws_size >= off);

  if (full) {
    zero_hist_k<<<NBINS / 1024, 256, 0, stream>>>((int4*)hist);
    prep_k<<<TBLOCKS + blocksAll, 256, 0, stream>>>(feats, featsT, coords, origin,
                                                    proj, hist, partials, out, N);
    scanA_k<<<257, 256, 0, stream>>>(hist, bsum, partials, blocksAll, scal);
    scanB_k<<<256, 256, 0, stream>>>(hist, bsum, ofs);
    scatter_k<<<blocksAll, 256, 0, stream>>>(coords, ofs, sorted, N);
    int gblocks = (N + 63) / 64;
    bp_gather_k<<<gblocks, 192, 0, stream>>>(sorted, origin, proj, featsT, scal, out, N);
  } else {
    stats_k<<<blocksAll, 256, 0, stream>>>(coords, origin, proj, partials, N);
    reduce_finalize_k<<<1, 1024, 0, stream>>>(partials, blocksAll, scal);
    bp_fallback_k<<<blocksAll, 256, 0, stream>>>(coords, origin, proj, feats, scal, out, N);
  }
}